// Round 1
// 452.062 us; speedup vs baseline: 1.1799x; 1.1799x over previous
//
#include <hip/hip_runtime.h>

// GCN-VAE encoder forward on MI355X — R5: cache-clustered CSR build.
//
// agg[d] = dinv[d] * ( hs[d] + sum_{s in N(d)} hs[s] ),  hs := h*dinv
// hs1, hs2 stored bf16 (RTN) -> gather traffic halves.
// hidden stored as bf16 hi+lo (exact split) -> GEMM2 keeps 3-term precision.
//
// CSR build (R5): group nodes into 512-node buckets (dst>>9). Pipeline:
//   group_count (LDS hist) -> goff_scan -> partition (per-WG counting sort,
//   coalesced staged writes) -> build_csr (per-group: hist/scan emits
//   cnt/dinv/rowptr, then places csr within a single 33KB L2-resident span).
// Replaces count/dinv/scan_block/scan_bsum/add_off/fill and their 16x
// write-amplified 4B scatter (107MB writes -> ~13MB).
//
// ws: hs1[N*128]bf | hidH[N*128]bf | hidL[N*128]bf | hs2[N*128]bf (aliased as
//     staged[E] during CSR build) | cnt[N] | dinv[N] | rowptr[N] |
//     cursor[N] (reused: ghist|gcur|goff) | bsum[512] | bcat[128] |
//     w1t_h/l[128*256]bf | wct_h/l[128*128]bf | csr[E]

#define TPB 256
#define GSHIFT 9
#define GSIZE 512
#define PART_M 8192  // edges per partition WG

typedef __attribute__((ext_vector_type(8))) short short8;
typedef __attribute__((ext_vector_type(4))) short short4v;
typedef __attribute__((ext_vector_type(4))) float floatx4;

__device__ __forceinline__ void split2(float v, short& hi, short& lo) {
    unsigned u = __float_as_uint(v);
    float hf = __uint_as_float(u & 0xFFFF0000u);
    float lf = v - hf;                       // exact
    hi = (short)(u >> 16);
    lo = (short)(__float_as_uint(lf) >> 16);
}

__device__ __forceinline__ short bf16_rtn(float v) {
    unsigned u = __float_as_uint(v);
    u += 0x7FFF + ((u >> 16) & 1);           // round to nearest even
    return (short)(u >> 16);
}

__device__ __forceinline__ void addrow(float* a, uint4 v) {
    a[0] += __uint_as_float(v.x << 16); a[1] += __uint_as_float(v.x & 0xFFFF0000u);
    a[2] += __uint_as_float(v.y << 16); a[3] += __uint_as_float(v.y & 0xFFFF0000u);
    a[4] += __uint_as_float(v.z << 16); a[5] += __uint_as_float(v.z & 0xFFFF0000u);
    a[6] += __uint_as_float(v.w << 16); a[7] += __uint_as_float(v.w & 0xFFFF0000u);
}

// ---------------- CSR build, stage 1: group-level histogram ----------------
__global__ __launch_bounds__(TPB) void group_count(const int* __restrict__ dst,
                                                   int* __restrict__ ghist, int E) {
    __shared__ int h[256];
    int t = threadIdx.x;
    h[t] = 0;
    __syncthreads();
    int stride = gridDim.x * TPB;
    for (int k = blockIdx.x * TPB + t; k < E; k += stride)
        atomicAdd(&h[dst[k] >> GSHIFT], 1);
    __syncthreads();
    if (h[t]) atomicAdd(&ghist[t], h[t]);
}

// ---------------- stage 2: exclusive scan of group counts ----------------
__global__ __launch_bounds__(256) void goff_scan(const int* __restrict__ ghist,
                                                 int* __restrict__ goff, int ngrp) {
    __shared__ int sc[256];
    int t = threadIdx.x;
    int v = (t < ngrp) ? ghist[t] : 0;
    sc[t] = v;
    __syncthreads();
#pragma unroll
    for (int off = 1; off < 256; off <<= 1) {
        int x = (t >= off) ? sc[t - off] : 0;
        __syncthreads();
        sc[t] += x;
        __syncthreads();
    }
    goff[t] = sc[t] - v;                 // exclusive; == E for t >= ngrp
    if (t == 255) goff[256] = sc[255];   // sentinel = E
}

// ---------------- stage 3: partition edges into group segments ----------------
// Per-WG counting sort of an 8192-edge slice; staged writes are contiguous runs.
__global__ __launch_bounds__(256) void partition_kernel(const int* __restrict__ src,
                                                        const int* __restrict__ dst,
                                                        const int* __restrict__ goff,
                                                        int* __restrict__ gcur,
                                                        int* __restrict__ staged, int E) {
    __shared__ int sorted[PART_M];
    __shared__ int sc[256];
    __shared__ int lstart[257];
    __shared__ int cur[256];
    __shared__ int gb[256];
    int t = threadIdx.x;
    int base = blockIdx.x * PART_M;
    int mloc = min(PART_M, E - base);

    sc[t] = 0;
    cur[t] = 0;
    __syncthreads();
    // phase 1: local group histogram
    for (int k = t; k < mloc; k += 256)
        atomicAdd(&sc[dst[base + k] >> GSHIFT], 1);
    __syncthreads();
    int v = sc[t];
    __syncthreads();
    sc[t] = v;
    __syncthreads();
#pragma unroll
    for (int off = 1; off < 256; off <<= 1) {
        int x = (t >= off) ? sc[t - off] : 0;
        __syncthreads();
        sc[t] += x;
        __syncthreads();
    }
    lstart[t] = sc[t] - v;               // exclusive local offsets
    if (t == 255) lstart[256] = sc[255]; // == mloc
    // phase 2b: reserve contiguous span in each group's global segment
    gb[t] = goff[t] + atomicAdd(&gcur[t], v);
    __syncthreads();
    // phase 3: place into LDS, bucket-sorted
    for (int k = t; k < mloc; k += 256) {
        int d = dst[base + k];
        int s = src[base + k];
        int b = d >> GSHIFT;
        int pos = lstart[b] + atomicAdd(&cur[b], 1);
        sorted[pos] = (s << GSHIFT) | (d & (GSIZE - 1));
    }
    __syncthreads();
    // phase 4: coalesced copy-out (binary search for bucket of entry e)
    for (int e = t; e < mloc; e += 256) {
        int lo = 0, hi = 256;
        while (hi - lo > 1) {
            int mid = (lo + hi) >> 1;
            if (lstart[mid] <= e) lo = mid; else hi = mid;
        }
        staged[gb[lo] + (e - lstart[lo])] = sorted[e];
    }
}

// ---------------- stage 4: per-group CSR finalize ----------------
// One WG per 512-node group: histogram -> scan emits cnt/dinv/rowptr, then
// scatter csr within the group's own (single-XCD, L2-resident) span.
__global__ __launch_bounds__(512) void build_csr(const int* __restrict__ staged,
                                                 const int* __restrict__ goff,
                                                 int* __restrict__ cnt,
                                                 float* __restrict__ dinv,
                                                 int* __restrict__ rowptr,
                                                 int* __restrict__ csr, int N) {
    __shared__ int hist[512];
    __shared__ int sc[512];
    __shared__ int lrow[512];
    __shared__ int cur[512];
    int t = threadIdx.x;
    int g = blockIdx.x;
    int s0 = goff[g], s1 = goff[g + 1];
    hist[t] = 0;
    cur[t] = 0;
    __syncthreads();
    for (int k = s0 + t; k < s1; k += 512)
        atomicAdd(&hist[staged[k] & (GSIZE - 1)], 1);
    __syncthreads();
    int v = hist[t];
    sc[t] = v;
    __syncthreads();
#pragma unroll
    for (int off = 1; off < 512; off <<= 1) {
        int x = (t >= off) ? sc[t - off] : 0;
        __syncthreads();
        sc[t] += x;
        __syncthreads();
    }
    int rp = s0 + sc[t] - v;             // global rowptr for this node
    lrow[t] = rp;
    int node = (g << GSHIFT) + t;
    if (node < N) {
        rowptr[node] = rp;
        cnt[node] = v;
        dinv[node] = rsqrtf(1.0f + (float)v);
    }
    __syncthreads();
    for (int k = s0 + t; k < s1; k += 512) {
        int p = staged[k];
        int dl = p & (GSIZE - 1);
        int pos = lrow[dl] + atomicAdd(&cur[dl], 1);
        csr[pos] = p >> GSHIFT;
    }
}

// ---------------- weight prep: transpose + hi/lo split ----------------
__global__ void prep_w1t(const float* __restrict__ w1, short* __restrict__ th,
                         short* __restrict__ tl) {
    int t = blockIdx.x * TPB + threadIdx.x;  // t < 128*256
    int k = t & 255, n = t >> 8;
    float v = w1[(size_t)k * 128 + n];
    short h, l;
    split2(v, h, l);
    th[t] = h;
    tl[t] = l;
}

__global__ void prep_wcatt(const float* __restrict__ w2, const float* __restrict__ b2,
                           const float* __restrict__ w3, const float* __restrict__ b3,
                           short* __restrict__ th, short* __restrict__ tl,
                           float* __restrict__ bcat) {
    int t = blockIdx.x * TPB + threadIdx.x;  // t < 128*128
    int k = t & 127, n = t >> 7;
    float v = (n < 64) ? w2[(size_t)k * 64 + n] : w3[(size_t)k * 64 + (n - 64)];
    short h, l;
    split2(v, h, l);
    th[t] = h;
    tl[t] = l;
    if (t < 64) { bcat[t] = b2[t]; bcat[64 + t] = b3[t]; }
}

// ---------------- MFMA GEMM1: Cb[M,128](bf16) = (A_f32[M,K] @ B) * rs[row] ----------------
// BM=64, BN=128, BK=32; 4 waves; 24 MFMA/k-step. LDS frag layout [kq][row][8].
__global__ __launch_bounds__(TPB) void gemm_mfma_f32in(const float* __restrict__ A,
                                                       const short* __restrict__ Bth,
                                                       const short* __restrict__ Btl,
                                                       const float* __restrict__ rs,
                                                       short* __restrict__ Cb, int M, int K) {
    __shared__ short Ah[4 * 64 * 8], Al[4 * 64 * 8];
    __shared__ short Bh[4 * 128 * 8], Bl[4 * 128 * 8];
    int t = threadIdx.x;
    int wave = t >> 6, lane = t & 63, quad = lane >> 4, l16 = lane & 15;
    int bm0 = blockIdx.x * 64;

    floatx4 acc[8];
#pragma unroll
    for (int nt = 0; nt < 8; ++nt) acc[nt] = (floatx4){0.f, 0.f, 0.f, 0.f};

    for (int k0 = 0; k0 < K; k0 += 32) {
        // stage A: 64 rows x 32 k f32 -> hi/lo bf16
#pragma unroll
        for (int i = 0; i < 2; ++i) {
            int c = t + i * 256;
            int row = c >> 3;
            int kc = (c & 7) * 4;
            int gr = bm0 + row;
            float4 v = (gr < M) ? *(const float4*)(A + (size_t)gr * K + k0 + kc)
                                : make_float4(0.f, 0.f, 0.f, 0.f);
            short h0, l0, h1, l1, h2, l2, h3, l3;
            split2(v.x, h0, l0);
            split2(v.y, h1, l1);
            split2(v.z, h2, l2);
            split2(v.w, h3, l3);
            int base = ((kc >> 3) * 64 + row) * 8 + (kc & 7);
            *(short4v*)&Ah[base] = (short4v){h0, h1, h2, h3};
            *(short4v*)&Al[base] = (short4v){l0, l1, l2, l3};
        }
        // stage B: already [n][k] bf16 hi/lo in global
#pragma unroll
        for (int i = 0; i < 2; ++i) {
            int c = t + i * 256;
            int n = c >> 2, kq = c & 3;
            size_t g = (size_t)n * K + k0 + kq * 8;
            int base = (kq * 128 + n) * 8;
            *(short8*)&Bh[base] = *(const short8*)(Bth + g);
            *(short8*)&Bl[base] = *(const short8*)(Btl + g);
        }
        __syncthreads();
        int am = wave * 16 + l16;
        short8 a_h = *(const short8*)&Ah[(quad * 64 + am) * 8];
        short8 a_l = *(const short8*)&Al[(quad * 64 + am) * 8];
#pragma unroll
        for (int nt = 0; nt < 8; ++nt) {
            int bn = nt * 16 + l16;
            short8 b_h = *(const short8*)&Bh[(quad * 128 + bn) * 8];
            short8 b_l = *(const short8*)&Bl[(quad * 128 + bn) * 8];
            acc[nt] = __builtin_amdgcn_mfma_f32_16x16x32_bf16(a_l, b_h, acc[nt], 0, 0, 0);
            acc[nt] = __builtin_amdgcn_mfma_f32_16x16x32_bf16(a_h, b_l, acc[nt], 0, 0, 0);
            acc[nt] = __builtin_amdgcn_mfma_f32_16x16x32_bf16(a_h, b_h, acc[nt], 0, 0, 0);
        }
        __syncthreads();
    }
#pragma unroll
    for (int reg = 0; reg < 4; ++reg) {
        int gr = bm0 + wave * 16 + quad * 4 + reg;
        if (gr < M) {
            float s = rs[gr];
            short* cp = Cb + (size_t)gr * 128;
#pragma unroll
            for (int nt = 0; nt < 8; ++nt) cp[nt * 16 + l16] = bf16_rtn(acc[nt][reg] * s);
        }
    }
}

// ---------------- MFMA GEMM2: Cb[M,128](bf16) = ((AH+AL)[M,K] @ B) * rs ----------------
// A pre-split bf16 hi/lo, layout [row][k]. K=128 here.
__global__ __launch_bounds__(TPB) void gemm_mfma_bfin(const short* __restrict__ AH,
                                                      const short* __restrict__ AL,
                                                      const short* __restrict__ Bth,
                                                      const short* __restrict__ Btl,
                                                      const float* __restrict__ rs,
                                                      short* __restrict__ Cb, int M, int K) {
    __shared__ short Ah[4 * 64 * 8], Al[4 * 64 * 8];
    __shared__ short Bh[4 * 128 * 8], Bl[4 * 128 * 8];
    int t = threadIdx.x;
    int wave = t >> 6, lane = t & 63, quad = lane >> 4, l16 = lane & 15;
    int bm0 = blockIdx.x * 64;

    floatx4 acc[8];
#pragma unroll
    for (int nt = 0; nt < 8; ++nt) acc[nt] = (floatx4){0.f, 0.f, 0.f, 0.f};

    for (int k0 = 0; k0 < K; k0 += 32) {
        // stage A: 64 rows x 32 k, straight uint4 copies of hi and lo
        {
            int row = t >> 2, kc = (t & 3) * 8;
            int gr = bm0 + row;
            uint4 vh = make_uint4(0u, 0u, 0u, 0u), vl = vh;
            if (gr < M) {
                size_t g = (size_t)gr * K + k0 + kc;
                vh = *(const uint4*)(AH + g);
                vl = *(const uint4*)(AL + g);
            }
            int base = ((kc >> 3) * 64 + row) * 8;
            *(uint4*)&Ah[base] = vh;
            *(uint4*)&Al[base] = vl;
        }
        // stage B
#pragma unroll
        for (int i = 0; i < 2; ++i) {
            int c = t + i * 256;
            int n = c >> 2, kq = c & 3;
            size_t g = (size_t)n * K + k0 + kq * 8;
            int base = (kq * 128 + n) * 8;
            *(short8*)&Bh[base] = *(const short8*)(Bth + g);
            *(short8*)&Bl[base] = *(const short8*)(Btl + g);
        }
        __syncthreads();
        int am = wave * 16 + l16;
        short8 a_h = *(const short8*)&Ah[(quad * 64 + am) * 8];
        short8 a_l = *(const short8*)&Al[(quad * 64 + am) * 8];
#pragma unroll
        for (int nt = 0; nt < 8; ++nt) {
            int bn = nt * 16 + l16;
            short8 b_h = *(const short8*)&Bh[(quad * 128 + bn) * 8];
            short8 b_l = *(const short8*)&Bl[(quad * 128 + bn) * 8];
            acc[nt] = __builtin_amdgcn_mfma_f32_16x16x32_bf16(a_l, b_h, acc[nt], 0, 0, 0);
            acc[nt] = __builtin_amdgcn_mfma_f32_16x16x32_bf16(a_h, b_l, acc[nt], 0, 0, 0);
            acc[nt] = __builtin_amdgcn_mfma_f32_16x16x32_bf16(a_h, b_h, acc[nt], 0, 0, 0);
        }
        __syncthreads();
    }
#pragma unroll
    for (int reg = 0; reg < 4; ++reg) {
        int gr = bm0 + wave * 16 + quad * 4 + reg;
        if (gr < M) {
            float s = rs[gr];
            short* cp = Cb + (size_t)gr * 128;
#pragma unroll
            for (int nt = 0; nt < 8; ++nt) cp[nt * 16 + l16] = bf16_rtn(acc[nt][reg] * s);
        }
    }
}

// ---------------- gather 1: hidden = relu(dinv*(self+sum nbrs) + b1) -> bf16 hi/lo ----------------
// 16 lanes per node; each lane covers 8 cols (one uint4 of bf16).
__global__ __launch_bounds__(TPB) void gather_hidden(const int* __restrict__ csr,
                                                     const int* __restrict__ rowptr,
                                                     const int* __restrict__ cnt,
                                                     const float* __restrict__ dinv,
                                                     const short* __restrict__ hs,
                                                     const float* __restrict__ b1,
                                                     short* __restrict__ hidH,
                                                     short* __restrict__ hidL, int N) {
    size_t t = (size_t)blockIdx.x * TPB + threadIdx.x;
    int nid = (int)(t >> 4);
    int lane = threadIdx.x & 15;
    if (nid >= N) return;
    int start = rowptr[nid];
    int deg = cnt[nid];
    const uint4* hp = (const uint4*)hs;  // row = 16 uint4
    float acc[8] = {0, 0, 0, 0, 0, 0, 0, 0};
    addrow(acc, hp[(size_t)nid * 16 + lane]);  // self term
    int j = 0;
    for (; j + 1 < deg; j += 2) {
        int s0 = csr[start + j], s1 = csr[start + j + 1];
        uint4 v0 = hp[(size_t)s0 * 16 + lane];
        uint4 v1 = hp[(size_t)s1 * 16 + lane];
        addrow(acc, v0);
        addrow(acc, v1);
    }
    if (j < deg) addrow(acc, hp[(size_t)csr[start + j] * 16 + lane]);
    float di = dinv[nid];
    float4 b0 = ((const float4*)b1)[lane * 2];
    float4 b1v = ((const float4*)b1)[lane * 2 + 1];
    float bb[8] = {b0.x, b0.y, b0.z, b0.w, b1v.x, b1v.y, b1v.z, b1v.w};
    unsigned hiw[8];
    short low[8];
#pragma unroll
    for (int i = 0; i < 8; ++i) {
        float h = fmaxf(fmaf(di, acc[i], bb[i]), 0.f);
        unsigned u = __float_as_uint(h);
        hiw[i] = u >> 16;
        float hf = __uint_as_float(u & 0xFFFF0000u);
        low[i] = bf16_rtn(h - hf);
    }
    uint4 ph, pl;
    ph.x = hiw[0] | (hiw[1] << 16);
    ph.y = hiw[2] | (hiw[3] << 16);
    ph.z = hiw[4] | (hiw[5] << 16);
    ph.w = hiw[6] | (hiw[7] << 16);
    pl.x = (unsigned short)low[0] | ((unsigned)(unsigned short)low[1] << 16);
    pl.y = (unsigned short)low[2] | ((unsigned)(unsigned short)low[3] << 16);
    pl.z = (unsigned short)low[4] | ((unsigned)(unsigned short)low[5] << 16);
    pl.w = (unsigned short)low[6] | ((unsigned)(unsigned short)low[7] << 16);
    ((uint4*)hidH)[(size_t)nid * 16 + lane] = ph;
    ((uint4*)hidL)[(size_t)nid * 16 + lane] = pl;
}

// ---------------- gather 2: out = dinv*(self+sum nbrs) + bcat -> f32 mu|logvar ----------------
__global__ __launch_bounds__(TPB) void gather_out(const int* __restrict__ csr,
                                                  const int* __restrict__ rowptr,
                                                  const int* __restrict__ cnt,
                                                  const float* __restrict__ dinv,
                                                  const short* __restrict__ hs,
                                                  const float* __restrict__ bcat,
                                                  float* __restrict__ out, int N) {
    size_t t = (size_t)blockIdx.x * TPB + threadIdx.x;
    int nid = (int)(t >> 4);
    int lane = threadIdx.x & 15;
    if (nid >= N) return;
    int start = rowptr[nid];
    int deg = cnt[nid];
    const uint4* hp = (const uint4*)hs;
    float acc[8] = {0, 0, 0, 0, 0, 0, 0, 0};
    addrow(acc, hp[(size_t)nid * 16 + lane]);
    int j = 0;
    for (; j + 1 < deg; j += 2) {
        int s0 = csr[start + j], s1 = csr[start + j + 1];
        uint4 v0 = hp[(size_t)s0 * 16 + lane];
        uint4 v1 = hp[(size_t)s1 * 16 + lane];
        addrow(acc, v0);
        addrow(acc, v1);
    }
    if (j < deg) addrow(acc, hp[(size_t)csr[start + j] * 16 + lane]);
    float di = dinv[nid];
    float4 b0 = ((const float4*)bcat)[lane * 2];
    float4 b1v = ((const float4*)bcat)[lane * 2 + 1];
    float4 r0, r1;
    r0.x = fmaf(di, acc[0], b0.x);
    r0.y = fmaf(di, acc[1], b0.y);
    r0.z = fmaf(di, acc[2], b0.z);
    r0.w = fmaf(di, acc[3], b0.w);
    r1.x = fmaf(di, acc[4], b1v.x);
    r1.y = fmaf(di, acc[5], b1v.y);
    r1.z = fmaf(di, acc[6], b1v.z);
    r1.w = fmaf(di, acc[7], b1v.w);
    int f = lane * 8;  // 0..120
    float* dp = (f < 64) ? (out + (size_t)nid * 64 + f)
                         : (out + (size_t)N * 64 + (size_t)nid * 64 + (f - 64));
    *(float4*)dp = r0;
    *(float4*)(dp + 4) = r1;
}

extern "C" void kernel_launch(void* const* d_in, const int* in_sizes, int n_in,
                              void* d_out, int out_size, void* d_ws, size_t ws_size,
                              hipStream_t stream) {
    const float* x  = (const float*)d_in[0];
    const float* w1 = (const float*)d_in[1];
    const float* b1 = (const float*)d_in[2];
    const float* w2 = (const float*)d_in[3];
    const float* b2 = (const float*)d_in[4];
    const float* w3 = (const float*)d_in[5];
    const float* b3 = (const float*)d_in[6];
    const int*   ei = (const int*)d_in[7];

    const int N = in_sizes[0] / 256;   // 100000
    const int E = in_sizes[7] / 2;     // 1600000
    const int K1 = 256;

    float* out = (float*)d_out;

    // workspace carve-up (layout unchanged from R4)
    size_t nh = (size_t)N * 128;
    short* hs1    = (short*)d_ws;          // N*128 bf16
    short* hidH   = hs1 + nh;
    short* hidL   = hidH + nh;
    short* hs2    = hidL + nh;
    int*   cnt    = (int*)(hs2 + nh);
    float* dinv   = (float*)(cnt + N);
    int*   rowptr = (int*)(dinv + N);
    int*   cursor = rowptr + N;            // reused: ghist | gcur | goff
    int*   bsum   = cursor + N;
    float* bcat   = (float*)(bsum + 512);
    short* w1t_h  = (short*)(bcat + 128);
    short* w1t_l  = w1t_h + 128 * 256;
    short* wct_h  = w1t_l + 128 * 256;
    short* wct_l  = wct_h + 128 * 128;
    int*   csr    = (int*)(wct_l + 128 * 128);

    const int* srcp = ei;
    const int* dstp = ei + E;

    const int ngrp = (N + GSIZE - 1) >> GSHIFT;   // 196
    int* ghist  = cursor;        // [256]
    int* gcur   = cursor + 256;  // [256]
    int* goff   = cursor + 512;  // [257]
    int* staged = (int*)hs2;     // alias: hs2 not live until gemm2

    // 0) zero group counters/cursors
    hipMemsetAsync(cursor, 0, 512 * sizeof(int), stream);

    // 1) CSR build: group hist -> scan -> partition -> per-group finalize
    int gc_blocks = (E + TPB * 16 - 1) / (TPB * 16);
    group_count<<<gc_blocks, TPB, 0, stream>>>(dstp, ghist, E);
    goff_scan<<<1, 256, 0, stream>>>(ghist, goff, ngrp);
    partition_kernel<<<(E + PART_M - 1) / PART_M, 256, 0, stream>>>(srcp, dstp, goff, gcur,
                                                                    staged, E);
    build_csr<<<ngrp, 512, 0, stream>>>(staged, goff, cnt, dinv, rowptr, csr, N);

    // 2) weight prep
    prep_w1t<<<(128 * 256) / TPB, TPB, 0, stream>>>(w1, w1t_h, w1t_l);
    prep_wcatt<<<(128 * 128) / TPB, TPB, 0, stream>>>(w2, b2, w3, b3, wct_h, wct_l, bcat);

    // 3) hs1 = (x @ w1) * dinv  -> bf16
    gemm_mfma_f32in<<<(N + 63) / 64, TPB, 0, stream>>>(x, w1t_h, w1t_l, dinv, hs1, N, K1);

    // 4) hidden = relu(dinv*(self+nbrs) + b1) -> hi/lo bf16
    size_t gthreads = (size_t)N * 16;
    gather_hidden<<<(unsigned)((gthreads + TPB - 1) / TPB), TPB, 0, stream>>>(
        csr, rowptr, cnt, dinv, hs1, b1, hidH, hidL, N);

    // 5) hs2 = (hidden @ wcat) * dinv -> bf16   (overwrites staged — dead by now)
    gemm_mfma_bfin<<<(N + 63) / 64, TPB, 0, stream>>>(hidH, hidL, wct_h, wct_l, dinv, hs2, N, 128);

    // 6) out = dinv*(self+nbrs) + bcat -> mu | logvar (f32)
    gather_out<<<(unsigned)((gthreads + TPB - 1) / TPB), TPB, 0, stream>>>(
        csr, rowptr, cnt, dinv, hs2, bcat, out, N);
}

// Round 2
// 430.147 us; speedup vs baseline: 1.2400x; 1.0509x over previous
//
#include <hip/hip_runtime.h>

// GCN-VAE encoder forward on MI355X — R6: pipelined MFMA GEMMs.
//
// agg[d] = dinv[d] * ( hs[d] + sum_{s in N(d)} hs[s] ),  hs := h*dinv
// hs1, hs2 stored bf16 (RTN) -> gather traffic halves.
// hidden stored as bf16 hi+lo (exact split) -> GEMM2 keeps 3-term precision.
//
// R6: both GEMMs restructured as 2-phase global_load_lds pipelines:
//   prologue STAGE(buf0); barrier; loop { STAGE(buf^1,next); ds_read+24 MFMA
//   on buf; barrier; } — one barrier/k-step, HBM latency hidden under MFMA.
//   LDS linear-dest constraint => bank conflicts fixed by pre-swizzling the
//   GLOBAL source granule column and XOR-ing the same on ds_read:
//     A f32 [64][32]  : col(16B granule) ^= (row & 7)      (2-way, free)
//     bf16  [R][32]   : col ^= ((row >> 1) & 3)            (2-way, free)
//
// CSR build (R5): group nodes into 512-node buckets (dst>>9):
//   group_count -> goff_scan -> partition (per-WG counting sort) ->
//   build_csr (per-group hist/scan emits cnt/dinv/rowptr + L2-local scatter).
//
// ws: hs1[N*128]bf | hidH[N*128]bf | hidL[N*128]bf | hs2[N*128]bf (aliased as
//     staged[E] during CSR build) | cnt[N] | dinv[N] | rowptr[N] |
//     cursor[N] (reused: ghist|gcur|goff) | bsum[512] | bcat[128] |
//     w1t_h/l[128*256]bf | wct_h/l[128*128]bf | csr[E]

#define TPB 256
#define GSHIFT 9
#define GSIZE 512
#define PART_M 8192  // edges per partition WG

typedef __attribute__((ext_vector_type(8))) short short8;
typedef __attribute__((ext_vector_type(4))) short short4v;
typedef __attribute__((ext_vector_type(4))) float floatx4;

__device__ __forceinline__ void split2(float v, short& hi, short& lo) {
    unsigned u = __float_as_uint(v);
    float hf = __uint_as_float(u & 0xFFFF0000u);
    float lf = v - hf;                       // exact
    hi = (short)(u >> 16);
    lo = (short)(__float_as_uint(lf) >> 16);
}

__device__ __forceinline__ short bf16_rtn(float v) {
    unsigned u = __float_as_uint(v);
    u += 0x7FFF + ((u >> 16) & 1);           // round to nearest even
    return (short)(u >> 16);
}

__device__ __forceinline__ void addrow(float* a, uint4 v) {
    a[0] += __uint_as_float(v.x << 16); a[1] += __uint_as_float(v.x & 0xFFFF0000u);
    a[2] += __uint_as_float(v.y << 16); a[3] += __uint_as_float(v.y & 0xFFFF0000u);
    a[4] += __uint_as_float(v.z << 16); a[5] += __uint_as_float(v.z & 0xFFFF0000u);
    a[6] += __uint_as_float(v.w << 16); a[7] += __uint_as_float(v.w & 0xFFFF0000u);
}

// async 16B global -> LDS (linear dest: wave-uniform base + lane*16)
__device__ __forceinline__ void gload_lds16(const void* g, void* l) {
    __builtin_amdgcn_global_load_lds(
        (const __attribute__((address_space(1))) unsigned int*)g,
        (__attribute__((address_space(3))) unsigned int*)l, 16, 0, 0);
}

// ---------------- CSR build, stage 1: group-level histogram ----------------
__global__ __launch_bounds__(TPB) void group_count(const int* __restrict__ dst,
                                                   int* __restrict__ ghist, int E) {
    __shared__ int h[256];
    int t = threadIdx.x;
    h[t] = 0;
    __syncthreads();
    int stride = gridDim.x * TPB;
    for (int k = blockIdx.x * TPB + t; k < E; k += stride)
        atomicAdd(&h[dst[k] >> GSHIFT], 1);
    __syncthreads();
    if (h[t]) atomicAdd(&ghist[t], h[t]);
}

// ---------------- stage 2: exclusive scan of group counts ----------------
__global__ __launch_bounds__(256) void goff_scan(const int* __restrict__ ghist,
                                                 int* __restrict__ goff, int ngrp) {
    __shared__ int sc[256];
    int t = threadIdx.x;
    int v = (t < ngrp) ? ghist[t] : 0;
    sc[t] = v;
    __syncthreads();
#pragma unroll
    for (int off = 1; off < 256; off <<= 1) {
        int x = (t >= off) ? sc[t - off] : 0;
        __syncthreads();
        sc[t] += x;
        __syncthreads();
    }
    goff[t] = sc[t] - v;                 // exclusive; == E for t >= ngrp
    if (t == 255) goff[256] = sc[255];   // sentinel = E
}

// ---------------- stage 3: partition edges into group segments ----------------
__global__ __launch_bounds__(256) void partition_kernel(const int* __restrict__ src,
                                                        const int* __restrict__ dst,
                                                        const int* __restrict__ goff,
                                                        int* __restrict__ gcur,
                                                        int* __restrict__ staged, int E) {
    __shared__ int sorted[PART_M];
    __shared__ int sc[256];
    __shared__ int lstart[257];
    __shared__ int cur[256];
    __shared__ int gb[256];
    int t = threadIdx.x;
    int base = blockIdx.x * PART_M;
    int mloc = min(PART_M, E - base);

    sc[t] = 0;
    cur[t] = 0;
    __syncthreads();
    for (int k = t; k < mloc; k += 256)
        atomicAdd(&sc[dst[base + k] >> GSHIFT], 1);
    __syncthreads();
    int v = sc[t];
    __syncthreads();
    sc[t] = v;
    __syncthreads();
#pragma unroll
    for (int off = 1; off < 256; off <<= 1) {
        int x = (t >= off) ? sc[t - off] : 0;
        __syncthreads();
        sc[t] += x;
        __syncthreads();
    }
    lstart[t] = sc[t] - v;
    if (t == 255) lstart[256] = sc[255];
    gb[t] = goff[t] + atomicAdd(&gcur[t], v);
    __syncthreads();
    for (int k = t; k < mloc; k += 256) {
        int d = dst[base + k];
        int s = src[base + k];
        int b = d >> GSHIFT;
        int pos = lstart[b] + atomicAdd(&cur[b], 1);
        sorted[pos] = (s << GSHIFT) | (d & (GSIZE - 1));
    }
    __syncthreads();
    for (int e = t; e < mloc; e += 256) {
        int lo = 0, hi = 256;
        while (hi - lo > 1) {
            int mid = (lo + hi) >> 1;
            if (lstart[mid] <= e) lo = mid; else hi = mid;
        }
        staged[gb[lo] + (e - lstart[lo])] = sorted[e];
    }
}

// ---------------- stage 4: per-group CSR finalize ----------------
__global__ __launch_bounds__(512) void build_csr(const int* __restrict__ staged,
                                                 const int* __restrict__ goff,
                                                 int* __restrict__ cnt,
                                                 float* __restrict__ dinv,
                                                 int* __restrict__ rowptr,
                                                 int* __restrict__ csr, int N) {
    __shared__ int hist[512];
    __shared__ int sc[512];
    __shared__ int lrow[512];
    __shared__ int cur[512];
    int t = threadIdx.x;
    int g = blockIdx.x;
    int s0 = goff[g], s1 = goff[g + 1];
    hist[t] = 0;
    cur[t] = 0;
    __syncthreads();
    for (int k = s0 + t; k < s1; k += 512)
        atomicAdd(&hist[staged[k] & (GSIZE - 1)], 1);
    __syncthreads();
    int v = hist[t];
    sc[t] = v;
    __syncthreads();
#pragma unroll
    for (int off = 1; off < 512; off <<= 1) {
        int x = (t >= off) ? sc[t - off] : 0;
        __syncthreads();
        sc[t] += x;
        __syncthreads();
    }
    int rp = s0 + sc[t] - v;
    lrow[t] = rp;
    int node = (g << GSHIFT) + t;
    if (node < N) {
        rowptr[node] = rp;
        cnt[node] = v;
        dinv[node] = rsqrtf(1.0f + (float)v);
    }
    __syncthreads();
    for (int k = s0 + t; k < s1; k += 512) {
        int p = staged[k];
        int dl = p & (GSIZE - 1);
        int pos = lrow[dl] + atomicAdd(&cur[dl], 1);
        csr[pos] = p >> GSHIFT;
    }
}

// ---------------- weight prep: transpose + hi/lo split ----------------
__global__ void prep_w1t(const float* __restrict__ w1, short* __restrict__ th,
                         short* __restrict__ tl) {
    int t = blockIdx.x * TPB + threadIdx.x;  // t < 128*256
    int k = t & 255, n = t >> 8;
    float v = w1[(size_t)k * 128 + n];
    short h, l;
    split2(v, h, l);
    th[t] = h;
    tl[t] = l;
}

__global__ void prep_wcatt(const float* __restrict__ w2, const float* __restrict__ b2,
                           const float* __restrict__ w3, const float* __restrict__ b3,
                           short* __restrict__ th, short* __restrict__ tl,
                           float* __restrict__ bcat) {
    int t = blockIdx.x * TPB + threadIdx.x;  // t < 128*128
    int k = t & 127, n = t >> 7;
    float v = (n < 64) ? w2[(size_t)k * 64 + n] : w3[(size_t)k * 64 + (n - 64)];
    short h, l;
    split2(v, h, l);
    th[t] = h;
    tl[t] = l;
    if (t < 64) { bcat[t] = b2[t]; bcat[64 + t] = b3[t]; }
}

// ---------------- MFMA GEMM1 (pipelined): Cb[M,128]bf = (A_f32[M,K] @ B) * rs ----------------
// BM=64, BN=128, BK=32, 4 waves. A staged f32 via global_load_lds (dbuf),
// split2 at fragment read. B (bf16 hi/lo, [n][k]) staged via global_load_lds.
__global__ __launch_bounds__(TPB) void gemm_mfma_f32in(const float* __restrict__ A,
                                                       const short* __restrict__ Bth,
                                                       const short* __restrict__ Btl,
                                                       const float* __restrict__ rs,
                                                       short* __restrict__ Cb, int M, int K) {
    __shared__ float Af[2][64 * 32];           // 2 x 8KB, granule col ^= (row&7)
    __shared__ short Bh[2][128 * 32];          // 2 x 8KB, granule col ^= ((row>>1)&3)
    __shared__ short Bl[2][128 * 32];
    int t = threadIdx.x;
    int wave = t >> 6, lane = t & 63, quad = lane >> 4, l16 = lane & 15;
    int bm0 = blockIdx.x * 64;

    floatx4 acc[8];
#pragma unroll
    for (int nt = 0; nt < 8; ++nt) acc[nt] = (floatx4){0.f, 0.f, 0.f, 0.f};

    auto stage = [&](int pb, int k0) {
        // A: 64x32 f32 = 512 granules of 16B, 2/thread
#pragma unroll
        for (int i = 0; i < 2; ++i) {
            int g = i * 256 + t;
            int row = g >> 3, col = g & 7;
            int gr = bm0 + row;
            if (gr >= M) gr = M - 1;           // clamp: no per-lane predication
            int scol = col ^ (row & 7);
            gload_lds16(A + (size_t)gr * K + k0 + scol * 4,
                        &Af[pb][(i * 256 + wave * 64) * 4]);
        }
        // B: 128x32 bf16 x2 = 512 granules each, 2/thread each
#pragma unroll
        for (int i = 0; i < 2; ++i) {
            int g = i * 256 + t;
            int row = g >> 2, col = g & 3;
            int scol = col ^ ((row >> 1) & 3);
            size_t off = (size_t)row * K + k0 + scol * 8;
            int lb = (i * 256 + wave * 64) * 8;
            gload_lds16(Bth + off, &Bh[pb][lb]);
            gload_lds16(Btl + off, &Bl[pb][lb]);
        }
    };

    int nk = K >> 5;
    stage(0, 0);
    __syncthreads();
    int am = wave * 16 + l16;
    int ac0 = ((quad * 2 + 0) ^ (am & 7)) * 4;
    int ac1 = ((quad * 2 + 1) ^ (am & 7)) * 4;
    int bc = (quad ^ ((l16 >> 1) & 3)) * 8;
    for (int ks = 0; ks < nk; ++ks) {
        int pb = ks & 1;
        if (ks + 1 < nk) stage(pb ^ 1, (ks + 1) << 5);
        float4 fa0 = *(const float4*)&Af[pb][am * 32 + ac0];
        float4 fa1 = *(const float4*)&Af[pb][am * 32 + ac1];
        short8 a_h, a_l;
        {
            short h, l;
            split2(fa0.x, h, l); a_h[0] = h; a_l[0] = l;
            split2(fa0.y, h, l); a_h[1] = h; a_l[1] = l;
            split2(fa0.z, h, l); a_h[2] = h; a_l[2] = l;
            split2(fa0.w, h, l); a_h[3] = h; a_l[3] = l;
            split2(fa1.x, h, l); a_h[4] = h; a_l[4] = l;
            split2(fa1.y, h, l); a_h[5] = h; a_l[5] = l;
            split2(fa1.z, h, l); a_h[6] = h; a_l[6] = l;
            split2(fa1.w, h, l); a_h[7] = h; a_l[7] = l;
        }
#pragma unroll
        for (int nt = 0; nt < 8; ++nt) {
            int bn = nt * 16 + l16;
            short8 b_h = *(const short8*)&Bh[pb][bn * 32 + bc];
            short8 b_l = *(const short8*)&Bl[pb][bn * 32 + bc];
            acc[nt] = __builtin_amdgcn_mfma_f32_16x16x32_bf16(a_l, b_h, acc[nt], 0, 0, 0);
            acc[nt] = __builtin_amdgcn_mfma_f32_16x16x32_bf16(a_h, b_l, acc[nt], 0, 0, 0);
            acc[nt] = __builtin_amdgcn_mfma_f32_16x16x32_bf16(a_h, b_h, acc[nt], 0, 0, 0);
        }
        __syncthreads();
    }
#pragma unroll
    for (int reg = 0; reg < 4; ++reg) {
        int gr = bm0 + wave * 16 + quad * 4 + reg;
        if (gr < M) {
            float s = rs[gr];
            short* cp = Cb + (size_t)gr * 128;
#pragma unroll
            for (int nt = 0; nt < 8; ++nt) cp[nt * 16 + l16] = bf16_rtn(acc[nt][reg] * s);
        }
    }
}

// ---------------- MFMA GEMM2 (pipelined): Cb[M,128]bf = ((AH+AL)[M,K] @ B) * rs ----------------
// A pre-split bf16 hi/lo [row][k]; all four tiles staged via global_load_lds.
__global__ __launch_bounds__(TPB) void gemm_mfma_bfin(const short* __restrict__ AH,
                                                      const short* __restrict__ AL,
                                                      const short* __restrict__ Bth,
                                                      const short* __restrict__ Btl,
                                                      const float* __restrict__ rs,
                                                      short* __restrict__ Cb, int M, int K) {
    __shared__ short Ah[2][64 * 32], Al[2][64 * 32];   // 2 x 4KB each
    __shared__ short Bh[2][128 * 32], Bl[2][128 * 32]; // 2 x 8KB each
    int t = threadIdx.x;
    int wave = t >> 6, lane = t & 63, quad = lane >> 4, l16 = lane & 15;
    int bm0 = blockIdx.x * 64;

    floatx4 acc[8];
#pragma unroll
    for (int nt = 0; nt < 8; ++nt) acc[nt] = (floatx4){0.f, 0.f, 0.f, 0.f};

    auto stage = [&](int pb, int k0) {
        // A: 64x32 shorts x2 = 256 granules each, 1/thread each
        {
            int row = t >> 2, col = t & 3;
            int gr = bm0 + row;
            if (gr >= M) gr = M - 1;
            int scol = col ^ ((row >> 1) & 3);
            size_t off = (size_t)gr * K + k0 + scol * 8;
            int lb = (wave * 64) * 8;
            gload_lds16(AH + off, &Ah[pb][lb]);
            gload_lds16(AL + off, &Al[pb][lb]);
        }
        // B: 128x32 shorts x2 = 512 granules each, 2/thread each
#pragma unroll
        for (int i = 0; i < 2; ++i) {
            int g = i * 256 + t;
            int row = g >> 2, col = g & 3;
            int scol = col ^ ((row >> 1) & 3);
            size_t off = (size_t)row * K + k0 + scol * 8;
            int lb = (i * 256 + wave * 64) * 8;
            gload_lds16(Bth + off, &Bh[pb][lb]);
            gload_lds16(Btl + off, &Bl[pb][lb]);
        }
    };

    int nk = K >> 5;
    stage(0, 0);
    __syncthreads();
    int am = wave * 16 + l16;
    int ac = (quad ^ ((am >> 1) & 3)) * 8;
    int bc = (quad ^ ((l16 >> 1) & 3)) * 8;
    for (int ks = 0; ks < nk; ++ks) {
        int pb = ks & 1;
        if (ks + 1 < nk) stage(pb ^ 1, (ks + 1) << 5);
        short8 a_h = *(const short8*)&Ah[pb][am * 32 + ac];
        short8 a_l = *(const short8*)&Al[pb][am * 32 + ac];
#pragma unroll
        for (int nt = 0; nt < 8; ++nt) {
            int bn = nt * 16 + l16;
            short8 b_h = *(const short8*)&Bh[pb][bn * 32 + bc];
            short8 b_l = *(const short8*)&Bl[pb][bn * 32 + bc];
            acc[nt] = __builtin_amdgcn_mfma_f32_16x16x32_bf16(a_l, b_h, acc[nt], 0, 0, 0);
            acc[nt] = __builtin_amdgcn_mfma_f32_16x16x32_bf16(a_h, b_l, acc[nt], 0, 0, 0);
            acc[nt] = __builtin_amdgcn_mfma_f32_16x16x32_bf16(a_h, b_h, acc[nt], 0, 0, 0);
        }
        __syncthreads();
    }
#pragma unroll
    for (int reg = 0; reg < 4; ++reg) {
        int gr = bm0 + wave * 16 + quad * 4 + reg;
        if (gr < M) {
            float s = rs[gr];
            short* cp = Cb + (size_t)gr * 128;
#pragma unroll
            for (int nt = 0; nt < 8; ++nt) cp[nt * 16 + l16] = bf16_rtn(acc[nt][reg] * s);
        }
    }
}

// ---------------- gather 1: hidden = relu(dinv*(self+sum nbrs) + b1) -> bf16 hi/lo ----------------
__global__ __launch_bounds__(TPB) void gather_hidden(const int* __restrict__ csr,
                                                     const int* __restrict__ rowptr,
                                                     const int* __restrict__ cnt,
                                                     const float* __restrict__ dinv,
                                                     const short* __restrict__ hs,
                                                     const float* __restrict__ b1,
                                                     short* __restrict__ hidH,
                                                     short* __restrict__ hidL, int N) {
    size_t t = (size_t)blockIdx.x * TPB + threadIdx.x;
    int nid = (int)(t >> 4);
    int lane = threadIdx.x & 15;
    if (nid >= N) return;
    int start = rowptr[nid];
    int deg = cnt[nid];
    const uint4* hp = (const uint4*)hs;  // row = 16 uint4
    float acc[8] = {0, 0, 0, 0, 0, 0, 0, 0};
    addrow(acc, hp[(size_t)nid * 16 + lane]);  // self term
    int j = 0;
    for (; j + 1 < deg; j += 2) {
        int s0 = csr[start + j], s1 = csr[start + j + 1];
        uint4 v0 = hp[(size_t)s0 * 16 + lane];
        uint4 v1 = hp[(size_t)s1 * 16 + lane];
        addrow(acc, v0);
        addrow(acc, v1);
    }
    if (j < deg) addrow(acc, hp[(size_t)csr[start + j] * 16 + lane]);
    float di = dinv[nid];
    float4 b0 = ((const float4*)b1)[lane * 2];
    float4 b1v = ((const float4*)b1)[lane * 2 + 1];
    float bb[8] = {b0.x, b0.y, b0.z, b0.w, b1v.x, b1v.y, b1v.z, b1v.w};
    unsigned hiw[8];
    short low[8];
#pragma unroll
    for (int i = 0; i < 8; ++i) {
        float h = fmaxf(fmaf(di, acc[i], bb[i]), 0.f);
        unsigned u = __float_as_uint(h);
        hiw[i] = u >> 16;
        float hf = __uint_as_float(u & 0xFFFF0000u);
        low[i] = bf16_rtn(h - hf);
    }
    uint4 ph, pl;
    ph.x = hiw[0] | (hiw[1] << 16);
    ph.y = hiw[2] | (hiw[3] << 16);
    ph.z = hiw[4] | (hiw[5] << 16);
    ph.w = hiw[6] | (hiw[7] << 16);
    pl.x = (unsigned short)low[0] | ((unsigned)(unsigned short)low[1] << 16);
    pl.y = (unsigned short)low[2] | ((unsigned)(unsigned short)low[3] << 16);
    pl.z = (unsigned short)low[4] | ((unsigned)(unsigned short)low[5] << 16);
    pl.w = (unsigned short)low[6] | ((unsigned)(unsigned short)low[7] << 16);
    ((uint4*)hidH)[(size_t)nid * 16 + lane] = ph;
    ((uint4*)hidL)[(size_t)nid * 16 + lane] = pl;
}

// ---------------- gather 2: out = dinv*(self+sum nbrs) + bcat -> f32 mu|logvar ----------------
__global__ __launch_bounds__(TPB) void gather_out(const int* __restrict__ csr,
                                                  const int* __restrict__ rowptr,
                                                  const int* __restrict__ cnt,
                                                  const float* __restrict__ dinv,
                                                  const short* __restrict__ hs,
                                                  const float* __restrict__ bcat,
                                                  float* __restrict__ out, int N) {
    size_t t = (size_t)blockIdx.x * TPB + threadIdx.x;
    int nid = (int)(t >> 4);
    int lane = threadIdx.x & 15;
    if (nid >= N) return;
    int start = rowptr[nid];
    int deg = cnt[nid];
    const uint4* hp = (const uint4*)hs;
    float acc[8] = {0, 0, 0, 0, 0, 0, 0, 0};
    addrow(acc, hp[(size_t)nid * 16 + lane]);
    int j = 0;
    for (; j + 1 < deg; j += 2) {
        int s0 = csr[start + j], s1 = csr[start + j + 1];
        uint4 v0 = hp[(size_t)s0 * 16 + lane];
        uint4 v1 = hp[(size_t)s1 * 16 + lane];
        addrow(acc, v0);
        addrow(acc, v1);
    }
    if (j < deg) addrow(acc, hp[(size_t)csr[start + j] * 16 + lane]);
    float di = dinv[nid];
    float4 b0 = ((const float4*)bcat)[lane * 2];
    float4 b1v = ((const float4*)bcat)[lane * 2 + 1];
    float4 r0, r1;
    r0.x = fmaf(di, acc[0], b0.x);
    r0.y = fmaf(di, acc[1], b0.y);
    r0.z = fmaf(di, acc[2], b0.z);
    r0.w = fmaf(di, acc[3], b0.w);
    r1.x = fmaf(di, acc[4], b1v.x);
    r1.y = fmaf(di, acc[5], b1v.y);
    r1.z = fmaf(di, acc[6], b1v.z);
    r1.w = fmaf(di, acc[7], b1v.w);
    int f = lane * 8;  // 0..120
    float* dp = (f < 64) ? (out + (size_t)nid * 64 + f)
                         : (out + (size_t)N * 64 + (size_t)nid * 64 + (f - 64));
    *(float4*)dp = r0;
    *(float4*)(dp + 4) = r1;
}

extern "C" void kernel_launch(void* const* d_in, const int* in_sizes, int n_in,
                              void* d_out, int out_size, void* d_ws, size_t ws_size,
                              hipStream_t stream) {
    const float* x  = (const float*)d_in[0];
    const float* w1 = (const float*)d_in[1];
    const float* b1 = (const float*)d_in[2];
    const float* w2 = (const float*)d_in[3];
    const float* b2 = (const float*)d_in[4];
    const float* w3 = (const float*)d_in[5];
    const float* b3 = (const float*)d_in[6];
    const int*   ei = (const int*)d_in[7];

    const int N = in_sizes[0] / 256;   // 100000
    const int E = in_sizes[7] / 2;     // 1600000
    const int K1 = 256;

    float* out = (float*)d_out;

    // workspace carve-up (layout unchanged)
    size_t nh = (size_t)N * 128;
    short* hs1    = (short*)d_ws;          // N*128 bf16
    short* hidH   = hs1 + nh;
    short* hidL   = hidH + nh;
    short* hs2    = hidL + nh;
    int*   cnt    = (int*)(hs2 + nh);
    float* dinv   = (float*)(cnt + N);
    int*   rowptr = (int*)(dinv + N);
    int*   cursor = rowptr + N;            // reused: ghist | gcur | goff
    int*   bsum   = cursor + N;
    float* bcat   = (float*)(bsum + 512);
    short* w1t_h  = (short*)(bcat + 128);
    short* w1t_l  = w1t_h + 128 * 256;
    short* wct_h  = w1t_l + 128 * 256;
    short* wct_l  = wct_h + 128 * 128;
    int*   csr    = (int*)(wct_l + 128 * 128);

    const int* srcp = ei;
    const int* dstp = ei + E;

    const int ngrp = (N + GSIZE - 1) >> GSHIFT;   // 196
    int* ghist  = cursor;        // [256]
    int* gcur   = cursor + 256;  // [256]
    int* goff   = cursor + 512;  // [257]
    int* staged = (int*)hs2;     // alias: hs2 not live until gemm2

    // 0) zero group counters/cursors
    hipMemsetAsync(cursor, 0, 512 * sizeof(int), stream);

    // 1) CSR build: group hist -> scan -> partition -> per-group finalize
    int gc_blocks = (E + TPB * 16 - 1) / (TPB * 16);
    group_count<<<gc_blocks, TPB, 0, stream>>>(dstp, ghist, E);
    goff_scan<<<1, 256, 0, stream>>>(ghist, goff, ngrp);
    partition_kernel<<<(E + PART_M - 1) / PART_M, 256, 0, stream>>>(srcp, dstp, goff, gcur,
                                                                    staged, E);
    build_csr<<<ngrp, 512, 0, stream>>>(staged, goff, cnt, dinv, rowptr, csr, N);

    // 2) weight prep
    prep_w1t<<<(128 * 256) / TPB, TPB, 0, stream>>>(w1, w1t_h, w1t_l);
    prep_wcatt<<<(128 * 128) / TPB, TPB, 0, stream>>>(w2, b2, w3, b3, wct_h, wct_l, bcat);

    // 3) hs1 = (x @ w1) * dinv  -> bf16
    gemm_mfma_f32in<<<(N + 63) / 64, TPB, 0, stream>>>(x, w1t_h, w1t_l, dinv, hs1, N, K1);

    // 4) hidden = relu(dinv*(self+nbrs) + b1) -> hi/lo bf16
    size_t gthreads = (size_t)N * 16;
    gather_hidden<<<(unsigned)((gthreads + TPB - 1) / TPB), TPB, 0, stream>>>(
        csr, rowptr, cnt, dinv, hs1, b1, hidH, hidL, N);

    // 5) hs2 = (hidden @ wcat) * dinv -> bf16   (overwrites staged — dead by now)
    gemm_mfma_bfin<<<(N + 63) / 64, TPB, 0, stream>>>(hidH, hidL, wct_h, wct_l, dinv, hs2, N, 128);

    // 6) out = dinv*(self+nbrs) + bcat -> mu | logvar (f32)
    gather_out<<<(unsigned)((gthreads + TPB - 1) / TPB), TPB, 0, stream>>>(
        csr, rowptr, cnt, dinv, hs2, bcat, out, N);
}